// Round 1
// baseline (159.500 us; speedup 1.0000x reference)
//
#include <hip/hip_runtime.h>

#define DD 512
#define BB 512

__device__ __forceinline__ float fexp2(float x) {
#if __has_builtin(__builtin_amdgcn_exp2f)
  return __builtin_amdgcn_exp2f(x);
#else
  return exp2f(x);
#endif
}

// ---------------- Kernel 1: img_t = tanh(img @ W^T + bias) ----------------
// Writes t into out[:, 1024:1536] (fp32 slice of the output buffer) so we
// don't depend on ws_size. Grid (16,16), 256 threads, 32x32 tile, 2x2/thread.
__global__ __launch_bounds__(256) void gemm_tanh_kernel(
    const float* __restrict__ img, const float* __restrict__ W,
    const float* __restrict__ bias, float* __restrict__ out) {
  __shared__ float As[32][33];
  __shared__ float Ws[32][33];
  const int tid = threadIdx.x;
  const int bx = blockIdx.x;  // output col tile (i of W rows)
  const int by = blockIdx.y;  // batch row tile
  const int tr = (tid >> 4) << 1;  // 0,2,...,30
  const int tc = (tid & 15) << 1;  // 0,2,...,30
  float acc00 = 0.f, acc01 = 0.f, acc10 = 0.f, acc11 = 0.f;

  for (int k0 = 0; k0 < DD; k0 += 32) {
#pragma unroll
    for (int l = tid; l < 1024; l += 256) {
      const int r = l >> 5, c = l & 31;
      As[r][c] = img[(by * 32 + r) * DD + k0 + c];
      Ws[r][c] = W[(bx * 32 + r) * DD + k0 + c];
    }
    __syncthreads();
#pragma unroll
    for (int k = 0; k < 32; ++k) {
      const float a0 = As[tr][k], a1 = As[tr + 1][k];
      const float w0 = Ws[tc][k], w1 = Ws[tc + 1][k];
      acc00 = fmaf(a0, w0, acc00);
      acc01 = fmaf(a0, w1, acc01);
      acc10 = fmaf(a1, w0, acc10);
      acc11 = fmaf(a1, w1, acc11);
    }
    __syncthreads();
  }
  const int row = by * 32 + tr;
  const int col = bx * 32 + tc;
  const float b0 = bias[col], b1 = bias[col + 1];
  out[row * 2048 + 1024 + col]           = tanhf(acc00 + b0);
  out[row * 2048 + 1024 + col + 1]       = tanhf(acc01 + b1);
  out[(row + 1) * 2048 + 1024 + col]     = tanhf(acc10 + b0);
  out[(row + 1) * 2048 + 1024 + col + 1] = tanhf(acc11 + b1);
}

// ---------------- Kernel 2: co-attention, one block per batch row ----------
__global__ __launch_bounds__(256) void coattn_kernel(
    const float* __restrict__ img, const float* __restrict__ audio,
    float* __restrict__ out) {
  const int bb = blockIdx.x;
  const int tid = threadIdx.x;
  __shared__ float tl[DD];  // t * log2(e)  (exp2 exponent scale)
  __shared__ float tw[DD];  // t            (C_audio weights numerator)
  __shared__ float aa[DD];  // audio row
  __shared__ float cw[DD];  // colsum_j -> a_j / colsum_j
  __shared__ float rw[DD];  // rowsum_i -> t_i / rowsum_i

  const float* trow = out + (size_t)bb * 2048 + 1024;  // t from kernel 1
  for (int i = tid; i < DD; i += 256) {
    const float tv = trow[i];
    tw[i] = tv;
    tl[i] = tv * 1.4426950408889634f;
    const float av = audio[bb * DD + i];
    aa[i] = av;
    // concat_proj part of the output (coalesced copies)
    out[(size_t)bb * 2048 + i]       = img[bb * DD + i];
    out[(size_t)bb * 2048 + 512 + i] = av;
  }
  __syncthreads();

  const float aj0 = aa[tid];
  const float aj1 = aa[tid + 256];

  // ---- pass 1a: column sums (thread owns cols tid, tid+256) ----
  {
    float s0 = 0.f, s1 = 0.f;
#pragma unroll 8
    for (int i = 0; i < DD; ++i) {
      const float t = tl[i];
      s0 += fexp2(t * aj0);
      s1 += fexp2(t * aj1);
    }
    cw[tid] = s0;
    cw[tid + 256] = s1;
  }

  // ---- pass 1b: row sums (thread owns rows tid, tid+256) ----
  {
    const float t0 = tl[tid], t1 = tl[tid + 256];
    float s0 = 0.f, s1 = 0.f;
#pragma unroll 8
    for (int j = 0; j < DD; ++j) {
      const float a = aa[j];
      s0 += fexp2(t0 * a);
      s1 += fexp2(t1 * a);
    }
    rw[tid] = s0;
    rw[tid + 256] = s1;
  }
  __syncthreads();

  // convert sums to weights: cw[j] = a_j/colsum_j ; rw[i] = t_i/rowsum_i
  for (int i = tid; i < DD; i += 256) {
    cw[i] = aa[i] / cw[i];
    rw[i] = tw[i] / rw[i];
  }
  __syncthreads();

  // ---- pass 2a: C_img[i] = sum_j (a_j/colsum_j) * exp(t_i a_j) ----
  {
    const float t0 = tl[tid], t1 = tl[tid + 256];
    float c0 = 0.f, c1 = 0.f;
#pragma unroll 8
    for (int j = 0; j < DD; ++j) {
      const float a = aa[j];
      const float w = cw[j];
      c0 = fmaf(w, fexp2(t0 * a), c0);
      c1 = fmaf(w, fexp2(t1 * a), c1);
    }
    out[(size_t)bb * 2048 + 1024 + tid]       = c0;
    out[(size_t)bb * 2048 + 1024 + tid + 256] = c1;
  }

  // ---- pass 2b: C_audio[j] = sum_i (t_i/rowsum_i) * exp(t_i a_j) ----
  {
    float d0 = 0.f, d1 = 0.f;
#pragma unroll 8
    for (int i = 0; i < DD; ++i) {
      const float t = tl[i];
      const float w = rw[i];
      d0 = fmaf(w, fexp2(t * aj0), d0);
      d1 = fmaf(w, fexp2(t * aj1), d1);
    }
    out[(size_t)bb * 2048 + 1536 + tid]       = d0;
    out[(size_t)bb * 2048 + 1536 + tid + 256] = d1;
  }
}

extern "C" void kernel_launch(void* const* d_in, const int* in_sizes, int n_in,
                              void* d_out, int out_size, void* d_ws, size_t ws_size,
                              hipStream_t stream) {
  const float* img   = (const float*)d_in[0];
  const float* audio = (const float*)d_in[1];
  const float* W     = (const float*)d_in[2];
  const float* bias  = (const float*)d_in[3];
  float* out = (float*)d_out;

  hipLaunchKernelGGL(gemm_tanh_kernel, dim3(16, 16), dim3(256), 0, stream,
                     img, W, bias, out);
  hipLaunchKernelGGL(coattn_kernel, dim3(BB), dim3(256), 0, stream,
                     img, audio, out);
}

// Round 2
// 79.385 us; speedup vs baseline: 2.0092x; 2.0092x over previous
//
#include <hip/hip_runtime.h>

#define K_TERMS 24

// 1/k! table (fp32)
#define INVF_INIT { \
  1.0f, 1.0f, 0.5f, 1.6666666666666666e-01f, 4.1666666666666664e-02f, \
  8.3333333333333332e-03f, 1.3888888888888889e-03f, 1.9841269841269841e-04f, \
  2.4801587301587302e-05f, 2.7557319223985893e-06f, 2.7557319223985888e-07f, \
  2.5052108385441720e-08f, 2.0876756987868098e-09f, 1.6059043836821613e-10f, \
  1.1470745597729725e-11f, 7.6471637318198164e-13f, 4.7794773323873852e-14f, \
  2.8114572543455206e-15f, 1.5619206968586225e-16f, 8.2206352466243295e-18f, \
  4.1103176233121648e-19f, 1.9572941063391263e-20f, 8.8967913924505741e-22f, \
  3.8681701706306835e-23f }

// ---------------- Kernel A: Wt = W^T (512x512 fp32) ----------------
__global__ __launch_bounds__(256) void transpose_w(const float* __restrict__ W,
                                                   float* __restrict__ Wt) {
  __shared__ float tile[32][33];
  const int bx = blockIdx.x, by = blockIdx.y;
  const int c = threadIdx.x & 31, r0 = threadIdx.x >> 5;
#pragma unroll
  for (int i = 0; i < 4; ++i) {
    const int r = r0 + 8 * i;
    tile[r][c] = W[(by * 32 + r) * 512 + bx * 32 + c];
  }
  __syncthreads();
#pragma unroll
  for (int i = 0; i < 4; ++i) {
    const int r = r0 + 8 * i;
    Wt[(bx * 32 + r) * 512 + by * 32 + c] = tile[c][r];  // Wt[p][s] = W[s][p]
  }
}

// ---------------- Kernel B: fused GEMV+tanh + moment-space co-attention ----
// One block = 2 batch rows. 512 threads (8 waves).
template <bool HAS_WT>
__global__ __launch_bounds__(512) void fused_kernel(
    const float* __restrict__ img, const float* __restrict__ audio,
    const float* __restrict__ W, const float* __restrict__ bias,
    const float* __restrict__ Wt, float* __restrict__ out) {
  const int tid = threadIdx.x;
  const int b0 = blockIdx.x * 2;  // batch rows b0, b0+1

  __shared__ float aL[2][512];    // audio rows
  __shared__ float tL[2][512];    // tanh(img@W^T+b) rows
  __shared__ float cwL[2][512];   // a_j / colsum_j
  __shared__ float rwL[2][512];   // t_i / rowsum_i
  __shared__ float red[4][128][8];          // GEMV k-split partials
  __shared__ float gT[2][K_TERMS], gA[2][K_TERMS];
  __shared__ float gS[2][K_TERMS], gR[2][K_TERMS];

  constexpr float INVF[K_TERMS] = INVF_INIT;

  // ---- phase 0: concat copies + stage audio in LDS ----
#pragma unroll
  for (int s = tid; s < 1024; s += 512) {
    const int r = s >> 9, i = s & 511;
    const float iv = img[(size_t)(b0 + r) * 512 + i];
    const float av = audio[(size_t)(b0 + r) * 512 + i];
    out[(size_t)(b0 + r) * 2048 + i] = iv;
    out[(size_t)(b0 + r) * 2048 + 512 + i] = av;
    aL[r][i] = av;
  }

  // ---- phase 1: GEMV (2 rows) with coalesced Wt loads, scalar img loads ----
  {
    const int q = tid & 127;   // e-quad: outputs 4q..4q+3
    const int kh = tid >> 7;   // k-range quarter (wave-uniform)
    const int kbase = __builtin_amdgcn_readfirstlane(kh) * 128;
    float4 acc0 = {0.f, 0.f, 0.f, 0.f};
    float4 acc1 = {0.f, 0.f, 0.f, 0.f};
    const float* i0p = img + (size_t)b0 * 512;
    const float* i1p = img + (size_t)(b0 + 1) * 512;
    for (int kk = 0; kk < 128; kk += 4) {
      const int k = kbase + kk;
      const float4 iv0 = *(const float4*)(i0p + k);  // uniform -> s_load
      const float4 iv1 = *(const float4*)(i1p + k);
      const float im0[4] = {iv0.x, iv0.y, iv0.z, iv0.w};
      const float im1[4] = {iv1.x, iv1.y, iv1.z, iv1.w};
#pragma unroll
      for (int u = 0; u < 4; ++u) {
        float4 w4;
        if (HAS_WT) {
          w4 = *(const float4*)(Wt + (size_t)(k + u) * 512 + 4 * q);
        } else {
          w4.x = W[(size_t)(4 * q + 0) * 512 + k + u];
          w4.y = W[(size_t)(4 * q + 1) * 512 + k + u];
          w4.z = W[(size_t)(4 * q + 2) * 512 + k + u];
          w4.w = W[(size_t)(4 * q + 3) * 512 + k + u];
        }
        acc0.x = fmaf(w4.x, im0[u], acc0.x);
        acc0.y = fmaf(w4.y, im0[u], acc0.y);
        acc0.z = fmaf(w4.z, im0[u], acc0.z);
        acc0.w = fmaf(w4.w, im0[u], acc0.w);
        acc1.x = fmaf(w4.x, im1[u], acc1.x);
        acc1.y = fmaf(w4.y, im1[u], acc1.y);
        acc1.z = fmaf(w4.z, im1[u], acc1.z);
        acc1.w = fmaf(w4.w, im1[u], acc1.w);
      }
    }
    *(float4*)&red[kh][q][0] = acc0;
    *(float4*)&red[kh][q][4] = acc1;
  }
  __syncthreads();
  // combine k-split partials, add bias, tanh -> tL
#pragma unroll
  for (int s = tid; s < 1024; s += 512) {
    const int q = s >> 3, c = s & 7;
    const int r = c >> 2, e = 4 * q + (c & 3);
    float v = red[0][q][c] + red[1][q][c] + red[2][q][c] + red[3][q][c];
    tL[r][e] = tanhf(v + bias[e]);
  }
  __syncthreads();

  const int wave = tid >> 6, lane = tid & 63;

  // ---- phase 2A: raw moments T_k = sum t^k, A_k = sum a^k (waves 0-3) ----
  if (wave < 4) {
    const int r = wave >> 1, typ = wave & 1;  // typ0: T (from tL), typ1: A (from aL)
    const float* src = typ ? aL[r] : tL[r];
    float part[K_TERMS];
#pragma unroll
    for (int k = 0; k < K_TERMS; ++k) part[k] = 0.f;
#pragma unroll
    for (int u = 0; u < 8; ++u) {
      const float x = src[lane + 64 * u];
      float p = x;
      part[1] += p;
#pragma unroll
      for (int k = 2; k < K_TERMS; ++k) { p *= x; part[k] += p; }
    }
#pragma unroll
    for (int m = 1; m < 64; m <<= 1) {
#pragma unroll
      for (int k = 1; k < K_TERMS; ++k) part[k] += __shfl_xor(part[k], m, 64);
    }
    if (lane == 0) {
      float* g = typ ? gA[r] : gT[r];
      g[0] = 512.0f;
#pragma unroll
      for (int k = 1; k < K_TERMS; ++k) g[k] = part[k] * INVF[k];
    }
  }
  __syncthreads();

  // ---- phase 2B: colsum/rowsum via Horner -> cw, rw ----
  {
    const int grp = tid >> 7, e0 = tid & 127;  // grp wave-uniform
    const int r = grp >> 1, kind = grp & 1;    // kind0: cw (x=a, g=gT); kind1: rw (x=t, g=gA)
    float g[K_TERMS];
    const float* gsrc = kind ? gA[r] : gT[r];
#pragma unroll
    for (int k = 0; k < K_TERMS; ++k) g[k] = gsrc[k];
    const float* xs = kind ? tL[r] : aL[r];
    float* dst = kind ? rwL[r] : cwL[r];
#pragma unroll
    for (int u = 0; u < 4; ++u) {
      const int e = e0 + 128 * u;
      const float x = xs[e];
      float s = g[K_TERMS - 1];
#pragma unroll
      for (int k = K_TERMS - 2; k >= 0; --k) s = fmaf(s, x, g[k]);
      dst[e] = x / s;
    }
  }
  __syncthreads();

  // ---- phase 2C: weighted moments S_k = sum cw*a^k, R_k = sum rw*t^k ----
  if (wave < 4) {
    const int r = wave >> 1, typ = wave & 1;  // typ0: S, typ1: R
    const float* xs = typ ? tL[r] : aL[r];
    const float* ws = typ ? rwL[r] : cwL[r];
    float part[K_TERMS];
#pragma unroll
    for (int k = 0; k < K_TERMS; ++k) part[k] = 0.f;
#pragma unroll
    for (int u = 0; u < 8; ++u) {
      const int i = lane + 64 * u;
      const float x = xs[i];
      float p = ws[i];
      part[0] += p;
#pragma unroll
      for (int k = 1; k < K_TERMS; ++k) { p *= x; part[k] += p; }
    }
#pragma unroll
    for (int m = 1; m < 64; m <<= 1) {
#pragma unroll
      for (int k = 0; k < K_TERMS; ++k) part[k] += __shfl_xor(part[k], m, 64);
    }
    if (lane == 0) {
      float* g = typ ? gR[r] : gS[r];
#pragma unroll
      for (int k = 0; k < K_TERMS; ++k) g[k] = part[k] * INVF[k];
    }
  }
  __syncthreads();

  // ---- phase 2D: outputs C_img (Horner in t, gS) / C_audio (Horner in a, gR) ----
  {
    const int grp = tid >> 7, e0 = tid & 127;
    const int r = grp >> 1, kind = grp & 1;  // kind0: C_img; kind1: C_audio
    float g[K_TERMS];
    const float* gsrc = kind ? gR[r] : gS[r];
#pragma unroll
    for (int k = 0; k < K_TERMS; ++k) g[k] = gsrc[k];
    const float* xs = kind ? aL[r] : tL[r];
    float* op = out + (size_t)(b0 + r) * 2048 + 1024 + kind * 512;
#pragma unroll
    for (int u = 0; u < 4; ++u) {
      const int e = e0 + 128 * u;
      const float x = xs[e];
      float s = g[K_TERMS - 1];
#pragma unroll
      for (int k = K_TERMS - 2; k >= 0; --k) s = fmaf(s, x, g[k]);
      op[e] = s;
    }
  }
}

extern "C" void kernel_launch(void* const* d_in, const int* in_sizes, int n_in,
                              void* d_out, int out_size, void* d_ws, size_t ws_size,
                              hipStream_t stream) {
  const float* img   = (const float*)d_in[0];
  const float* audio = (const float*)d_in[1];
  const float* W     = (const float*)d_in[2];
  const float* bias  = (const float*)d_in[3];
  float* out = (float*)d_out;
  float* Wt = (float*)d_ws;

  if (ws_size >= (size_t)(1 << 20)) {
    hipLaunchKernelGGL(transpose_w, dim3(16, 16), dim3(256), 0, stream, W, Wt);
    hipLaunchKernelGGL((fused_kernel<true>), dim3(256), dim3(512), 0, stream,
                       img, audio, W, bias, Wt, out);
  } else {
    hipLaunchKernelGGL((fused_kernel<false>), dim3(256), dim3(512), 0, stream,
                       img, audio, W, bias, (const float*)nullptr, out);
  }
}

// Round 3
// 76.251 us; speedup vs baseline: 2.0918x; 1.0411x over previous
//
#include <hip/hip_runtime.h>

#define K_TERMS 24

// 1/k! table (fp32)
#define INVF_INIT { \
  1.0f, 1.0f, 0.5f, 1.6666666666666666e-01f, 4.1666666666666664e-02f, \
  8.3333333333333332e-03f, 1.3888888888888889e-03f, 1.9841269841269841e-04f, \
  2.4801587301587302e-05f, 2.7557319223985893e-06f, 2.7557319223985888e-07f, \
  2.5052108385441720e-08f, 2.0876756987868098e-09f, 1.6059043836821613e-10f, \
  1.1470745597729725e-11f, 7.6471637318198164e-13f, 4.7794773323873852e-14f, \
  2.8114572543455206e-15f, 1.5619206968586225e-16f, 8.2206352466243295e-18f, \
  4.1103176233121648e-19f, 1.9572941063391263e-20f, 8.8967913924505741e-22f, \
  3.8681701706306835e-23f }

typedef __attribute__((ext_vector_type(4))) float floatx4;
typedef __attribute__((ext_vector_type(8))) short short8;

__device__ __forceinline__ unsigned short f2bf_rn(float f) {
  union { float f; unsigned u; } v; v.f = f;
  const unsigned r = v.u + 0x7FFFu + ((v.u >> 16) & 1u);
  return (unsigned short)(r >> 16);
}

// ---------------- Kernel 1: t = tanh(img @ W^T + b) via bf16 MFMA ---------
// NT GEMM: both img[b][k] and W[e][k] are k-contiguous -> no transpose.
// Grid (16 e-tiles, 16 b-tiles), 256 threads, 32x32 tile, 1 MFMA quad/wave.
__global__ __launch_bounds__(256) void gemm_tanh_mfma(
    const float* __restrict__ img, const float* __restrict__ W,
    const float* __restrict__ bias, float* __restrict__ tdst, int tstride) {
  // row stride 40 shorts = 80 B: 16B-aligned for b128, bank-friendly.
  __shared__ unsigned short Abf[32][40];
  __shared__ unsigned short Wbf[32][40];
  const int tid = threadIdx.x;
  const int bx = blockIdx.x;       // e-tile
  const int by = blockIdx.y;       // b-tile
  const int r  = tid >> 3;         // staging row 0..31
  const int c4 = (tid & 7) * 4;    // staging col 0,4,...,28
  const int lane = tid & 63;
  const int wv = tid >> 6;         // wave 0..3
  const int bm = (wv >> 1) * 16;   // C quadrant row base
  const int en = (wv & 1) * 16;    // C quadrant col base
  const int frow = lane & 15;      // fragment m / n
  const int kg = lane >> 4;        // k-group 0..3 (8 elems each)

  floatx4 acc = {0.f, 0.f, 0.f, 0.f};
  const float* aprow = img + (size_t)(by * 32 + r) * 512;
  const float* wprow = W   + (size_t)(bx * 32 + r) * 512;

  for (int k0 = 0; k0 < 512; k0 += 32) {
    const float4 av = *(const float4*)(aprow + k0 + c4);
    const float4 wl = *(const float4*)(wprow + k0 + c4);
    __syncthreads();  // previous iteration's fragment reads complete
    ushort4 ab, wb;
    ab.x = f2bf_rn(av.x); ab.y = f2bf_rn(av.y);
    ab.z = f2bf_rn(av.z); ab.w = f2bf_rn(av.w);
    wb.x = f2bf_rn(wl.x); wb.y = f2bf_rn(wl.y);
    wb.z = f2bf_rn(wl.z); wb.w = f2bf_rn(wl.w);
    *(ushort4*)&Abf[r][c4] = ab;
    *(ushort4*)&Wbf[r][c4] = wb;
    __syncthreads();  // staging visible
    const short8 afrag = *(const short8*)&Abf[bm + frow][kg * 8];
    const short8 wfrag = *(const short8*)&Wbf[en + frow][kg * 8];
    acc = __builtin_amdgcn_mfma_f32_16x16x32_bf16(afrag, wfrag, acc, 0, 0, 0);
  }

  // C/D layout: col = lane&15, row = (lane>>4)*4 + reg  [measured m89/m91]
  const int e = bx * 32 + en + frow;
  const float bv = bias[e];
  const int b_base = by * 32 + bm + kg * 4;
#pragma unroll
  for (int i = 0; i < 4; ++i) {
    tdst[(size_t)(b_base + i) * tstride + e] = tanhf(acc[i] + bv);
  }
}

// ---------------- Kernel 2: moment-space co-attention (2 rows/block) ------
__global__ __launch_bounds__(512) void coattn_moments(
    const float* __restrict__ img, const float* __restrict__ audio,
    const float* __restrict__ tsrc, int tstride, float* __restrict__ out) {
  const int tid = threadIdx.x;
  const int b0 = blockIdx.x * 2;

  __shared__ float aL[2][512];    // audio rows
  __shared__ float tL[2][512];    // tanh rows (from kernel 1)
  __shared__ float cwL[2][512];   // a_j / colsum_j
  __shared__ float rwL[2][512];   // t_i / rowsum_i
  __shared__ float gT[2][K_TERMS], gA[2][K_TERMS];
  __shared__ float gS[2][K_TERMS], gR[2][K_TERMS];

  constexpr float INVF[K_TERMS] = INVF_INIT;

  // ---- phase 0: concat copies + stage audio and t ----
#pragma unroll
  for (int s = tid; s < 1024; s += 512) {
    const int r = s >> 9, i = s & 511;
    const float iv = img[(size_t)(b0 + r) * 512 + i];
    const float av = audio[(size_t)(b0 + r) * 512 + i];
    out[(size_t)(b0 + r) * 2048 + i] = iv;
    out[(size_t)(b0 + r) * 2048 + 512 + i] = av;
    aL[r][i] = av;
    tL[r][i] = tsrc[(size_t)(b0 + r) * tstride + i];
  }
  __syncthreads();

  const int wave = tid >> 6, lane = tid & 63;

  // ---- phase 2A: raw moments T_k = sum t^k, A_k = sum a^k (waves 0-3) ----
  if (wave < 4) {
    const int r = wave >> 1, typ = wave & 1;  // typ0: T (tL), typ1: A (aL)
    const float* src = typ ? aL[r] : tL[r];
    float part[K_TERMS];
#pragma unroll
    for (int k = 0; k < K_TERMS; ++k) part[k] = 0.f;
#pragma unroll
    for (int u = 0; u < 8; ++u) {
      const float x = src[lane + 64 * u];
      float p = x;
      part[1] += p;
#pragma unroll
      for (int k = 2; k < K_TERMS; ++k) { p *= x; part[k] += p; }
    }
#pragma unroll
    for (int m = 1; m < 64; m <<= 1) {
#pragma unroll
      for (int k = 1; k < K_TERMS; ++k) part[k] += __shfl_xor(part[k], m, 64);
    }
    if (lane == 0) {
      float* g = typ ? gA[r] : gT[r];
      g[0] = 512.0f;
#pragma unroll
      for (int k = 1; k < K_TERMS; ++k) g[k] = part[k] * INVF[k];
    }
  }
  __syncthreads();

  // ---- phase 2B: colsum/rowsum via Horner -> cw, rw ----
  {
    const int grp = tid >> 7, e0 = tid & 127;
    const int r = grp >> 1, kind = grp & 1;  // kind0: cw (x=a,g=gT); kind1: rw (x=t,g=gA)
    float g[K_TERMS];
    const float* gsrc = kind ? gA[r] : gT[r];
#pragma unroll
    for (int k = 0; k < K_TERMS; ++k) g[k] = gsrc[k];
    const float* xs = kind ? tL[r] : aL[r];
    float* dst = kind ? rwL[r] : cwL[r];
#pragma unroll
    for (int u = 0; u < 4; ++u) {
      const int e = e0 + 128 * u;
      const float x = xs[e];
      float s = g[K_TERMS - 1];
#pragma unroll
      for (int k = K_TERMS - 2; k >= 0; --k) s = fmaf(s, x, g[k]);
      dst[e] = x / s;
    }
  }
  __syncthreads();

  // ---- phase 2C: weighted moments S_k = sum cw*a^k, R_k = sum rw*t^k ----
  if (wave < 4) {
    const int r = wave >> 1, typ = wave & 1;  // typ0: S, typ1: R
    const float* xs = typ ? tL[r] : aL[r];
    const float* ws = typ ? rwL[r] : cwL[r];
    float part[K_TERMS];
#pragma unroll
    for (int k = 0; k < K_TERMS; ++k) part[k] = 0.f;
#pragma unroll
    for (int u = 0; u < 8; ++u) {
      const int i = lane + 64 * u;
      const float x = xs[i];
      float p = ws[i];
      part[0] += p;
#pragma unroll
      for (int k = 1; k < K_TERMS; ++k) { p *= x; part[k] += p; }
    }
#pragma unroll
    for (int m = 1; m < 64; m <<= 1) {
#pragma unroll
      for (int k = 0; k < K_TERMS; ++k) part[k] += __shfl_xor(part[k], m, 64);
    }
    if (lane == 0) {
      float* g = typ ? gR[r] : gS[r];
#pragma unroll
      for (int k = 0; k < K_TERMS; ++k) g[k] = part[k] * INVF[k];
    }
  }
  __syncthreads();

  // ---- phase 2D: outputs C_img (Horner in t, gS) / C_audio (Horner in a, gR)
  {
    const int grp = tid >> 7, e0 = tid & 127;
    const int r = grp >> 1, kind = grp & 1;  // kind0: C_img; kind1: C_audio
    float g[K_TERMS];
    const float* gsrc = kind ? gR[r] : gS[r];
#pragma unroll
    for (int k = 0; k < K_TERMS; ++k) g[k] = gsrc[k];
    const float* xs = kind ? aL[r] : tL[r];
    float* op = out + (size_t)(b0 + r) * 2048 + 1024 + kind * 512;
#pragma unroll
    for (int u = 0; u < 4; ++u) {
      const int e = e0 + 128 * u;
      const float x = xs[e];
      float s = g[K_TERMS - 1];
#pragma unroll
      for (int k = K_TERMS - 2; k >= 0; --k) s = fmaf(s, x, g[k]);
      op[e] = s;
    }
  }
}

extern "C" void kernel_launch(void* const* d_in, const int* in_sizes, int n_in,
                              void* d_out, int out_size, void* d_ws, size_t ws_size,
                              hipStream_t stream) {
  const float* img   = (const float*)d_in[0];
  const float* audio = (const float*)d_in[1];
  const float* W     = (const float*)d_in[2];
  const float* bias  = (const float*)d_in[3];
  float* out = (float*)d_out;

  float* tdst;
  int tstride;
  if (ws_size >= (size_t)(512 * 512 * 4)) {
    tdst = (float*)d_ws;
    tstride = 512;
  } else {
    // fallback: park t in the out[:,1024:1536] slice; K2 reads it in phase 0
    // (before phase 2D overwrites that slice with C_img).
    tdst = out + 1024;
    tstride = 2048;
  }

  hipLaunchKernelGGL(gemm_tanh_mfma, dim3(16, 16), dim3(256), 0, stream,
                     img, W, bias, tdst, tstride);
  hipLaunchKernelGGL(coattn_moments, dim3(256), dim3(512), 0, stream,
                     img, audio, tdst, tstride, out);
}